// Round 2
// baseline (485.128 us; speedup 1.0000x reference)
//
#include <hip/hip_runtime.h>

constexpr int cB = 32;
constexpr int cS = 1024;
constexpr int cD = 1280;
constexpr int KC = 16;          // k-chunk for split-K qk matmul
constexpr int NKC = cD / KC;    // 80 k-chunks
constexpr int NNC = cD / 256;   // 5 n-chunks
constexpr int GB = 640;         // grid for merged kernels (<= 768 = 3 blk/CU * 256 CU)

#define LN_EPS 1e-5f
#define MASK_FILL -1e9f
#define SCALE 0.02795084971874737f   // 1280^-0.5

// ============================================================================
// Manual grid barrier: device-scope atomics + agent fences (cross-XCD safe).
// Co-residency guaranteed: grid 640 <= 768 slots from __launch_bounds__(256,3).
// cnt and sense in separate cache lines. Monotone phase ids; last arriver
// resets cnt (safe: every block incremented before any block can re-enter).
// ============================================================================
__device__ __forceinline__ void gbar(int* cnt, int* sense, int nblk, int ph) {
    __syncthreads();
    if (threadIdx.x == 0) {
        __threadfence();                               // release (wbL2)
        if (atomicAdd(cnt, 1) == nblk - 1) {
            atomicExch(cnt, 0);                        // reset for next barrier
            __threadfence();
            atomicExch(sense, ph);                     // release the spinners
        } else {
            while (atomicAdd(sense, 0) < ph)           // coherent read
                __builtin_amdgcn_s_sleep(32);
        }
        __threadfence();                               // acquire (invL2)
    }
    __syncthreads();
}

// ============================================================================
// Row-dot matmul vs W^T (wave-level body, verbatim from verified k_dotT):
//   out[b*cD+n] = bias[n] + dot(A[b,:], W[n,:])
// 2560 waves: wave owns one W row (read once into regs), loops 16 batches.
// ============================================================================
__device__ __forceinline__ void dotT_wave(const float* __restrict__ A, size_t lda,
                                          const float* __restrict__ W,
                                          const float* __restrict__ bias,
                                          float* __restrict__ out,
                                          int bid, int tid) {
    int w = tid >> 6, lane = tid & 63;
    int gw = bid * 4 + w;                   // 0..2559
    int n = gw >> 1;                        // W row
    int bh = (gw & 1) * 16;                 // batch half
    int d0 = lane * 4;

    float4 wr[5];
#pragma unroll
    for (int it = 0; it < 5; ++it)
        wr[it] = *reinterpret_cast<const float4*>(W + (size_t)n * cD + it * 256 + d0);
    float bn = bias[n];

#pragma unroll
    for (int bi = 0; bi < 16; ++bi) {
        int b = bh + bi;
        const float* a = A + (size_t)b * lda + d0;
        float4 av[5];
#pragma unroll
        for (int it = 0; it < 5; ++it)
            av[it] = *reinterpret_cast<const float4*>(a + it * 256);
        float dot = 0.f;
#pragma unroll
        for (int it = 0; it < 5; ++it)
            dot += av[it].x * wr[it].x + av[it].y * wr[it].y
                 + av[it].z * wr[it].z + av[it].w * wr[it].w;
#pragma unroll
        for (int off = 32; off; off >>= 1) dot += __shfl_xor(dot, off, 64);
        if (lane == 0) out[b * cD + n] = dot + bn;
    }
}

// ============================================================================
// Merged pre-attention chain: q0 -> split-K qk partials -> reduce + qb.
// Grid 640 x 256, all blocks co-resident; manual barriers ph=1,2.
// ============================================================================
__global__ __launch_bounds__(256, 3) void k_pre(const float* __restrict__ emb,
                                                const float* __restrict__ Wq,
                                                const float* __restrict__ bq,
                                                const float* __restrict__ Wk,
                                                const float* __restrict__ bk,
                                                float* __restrict__ q0,
                                                float* __restrict__ part,
                                                float* __restrict__ qk,
                                                float* __restrict__ qb,
                                                int* gsync) {
    int bid = blockIdx.x, tid = threadIdx.x;
    int* cnt = gsync;            // cache line 0
    int* sense = gsync + 32;     // cache line 1 (128 B apart)

    // ---- phase 1: q0 = emb[:,0,:] @ Wq^T + bq (all 640 blocks) ----
    dotT_wave(emb, (size_t)cS * cD, Wq, bq, q0, bid, tid);
    gbar(cnt, sense, GB, 1);

    // ---- phase 2: split-K partials, part[kc][b][n] (400 blocks) ----
    if (bid < NNC * NKC) {
        int nc = bid % NNC, kc = bid / NNC;
        int n0 = nc * 256, k0 = kc * KC;
        float w[KC];
#pragma unroll
        for (int kk = 0; kk < KC; ++kk)
            w[kk] = Wk[(size_t)(k0 + kk) * cD + n0 + tid];   // coalesced
#pragma unroll
        for (int b = 0; b < cB; ++b) {
            const float* Ab = q0 + (size_t)b * cD + k0;      // wave-uniform -> s_load
            float a0 = 0.f, a1 = 0.f, a2 = 0.f, a3 = 0.f;
#pragma unroll
            for (int kk = 0; kk < KC; kk += 4) {
                a0 += Ab[kk + 0] * w[kk + 0];
                a1 += Ab[kk + 1] * w[kk + 1];
                a2 += Ab[kk + 2] * w[kk + 2];
                a3 += Ab[kk + 3] * w[kk + 3];
            }
            part[(size_t)kc * (cB * cD) + b * cD + n0 + tid] = (a0 + a1) + (a2 + a3);
        }
    }
    gbar(cnt, sense, GB, 2);

    // ---- phase 3: qk = sum partials (160 blocks); qb = q0.bk (block 160) ----
    if (bid < 160) {
        int i = bid * 256 + tid;                // 0..cB*cD-1
        float s = 0.f;
#pragma unroll
        for (int c = 0; c < NKC; ++c) s += part[(size_t)c * (cB * cD) + i];
        qk[i] = s;
    } else if (bid == 160) {
        int w = tid >> 6, lane = tid & 63;
        int d0 = lane * 4;
        float4 bkr[5];
#pragma unroll
        for (int it = 0; it < 5; ++it)
            bkr[it] = *reinterpret_cast<const float4*>(bk + it * 256 + d0);
#pragma unroll
        for (int r = 0; r < 8; ++r) {
            int b = w * 8 + r;
            float dot = 0.f;
#pragma unroll
            for (int it = 0; it < 5; ++it) {
                float4 qv = *reinterpret_cast<const float4*>(q0 + b * cD + it * 256 + d0);
                dot += qv.x * bkr[it].x + qv.y * bkr[it].y
                     + qv.z * bkr[it].z + qv.w * bkr[it].w;
            }
#pragma unroll
            for (int off = 32; off; off >>= 1) dot += __shfl_xor(dot, off, 64);
            if (lane == 0) qb[b] = dot;
        }
    }
}

// ============================================================================
// Fused flash-style: scores + online softmax + weighted emb sum. UNCHANGED
// (verbatim from the verified 346 us kernel).
// ============================================================================
__global__ __launch_bounds__(256) void k_attn(const float* __restrict__ emb,
                                              const float* __restrict__ qk,
                                              const float* __restrict__ qb,
                                              const int* __restrict__ mask,
                                              float* __restrict__ pm,
                                              float* __restrict__ pl,
                                              float* __restrict__ pacc) {
    __shared__ float s_all[4][cD];
    __shared__ float s_m[4], s_l[4];
    int blk = blockIdx.x;
    int b = blk >> 5, sc = blk & 31;
    int w = threadIdx.x >> 6, lane = threadIdx.x & 63;
    int d0 = lane * 4;

    float4 qkr[5];
#pragma unroll
    for (int it = 0; it < 5; ++it)
        qkr[it] = *reinterpret_cast<const float4*>(qk + b * cD + it * 256 + d0);
    float qbv = qb[b];

    float m = -INFINITY, l = 0.f;
    float4 acc[5];
#pragma unroll
    for (int it = 0; it < 5; ++it) acc[it] = make_float4(0.f, 0.f, 0.f, 0.f);

    int s0 = sc * 32 + w * 8;
    for (int r = 0; r < 8; ++r) {
        int s = s0 + r;
        const float* e = emb + (size_t)(b * cS + s) * cD + d0;
        float4 er[5];
#pragma unroll
        for (int it = 0; it < 5; ++it)
            er[it] = *reinterpret_cast<const float4*>(e + it * 256);
        float dot = 0.f;
#pragma unroll
        for (int it = 0; it < 5; ++it)
            dot += er[it].x * qkr[it].x + er[it].y * qkr[it].y
                 + er[it].z * qkr[it].z + er[it].w * qkr[it].w;
#pragma unroll
        for (int off = 32; off; off >>= 1) dot += __shfl_xor(dot, off, 64);
        float scv = (mask[b * cS + s] == 0) ? MASK_FILL : (dot + qbv) * SCALE;
        if (scv > m) {                       // wave-uniform (dot is broadcast)
            float f = __expf(m - scv);
            l *= f;
#pragma unroll
            for (int it = 0; it < 5; ++it) {
                acc[it].x *= f; acc[it].y *= f; acc[it].z *= f; acc[it].w *= f;
            }
            m = scv;
        }
        float p = __expf(scv - m);
        l += p;
#pragma unroll
        for (int it = 0; it < 5; ++it) {
            acc[it].x += p * er[it].x; acc[it].y += p * er[it].y;
            acc[it].z += p * er[it].z; acc[it].w += p * er[it].w;
        }
    }

    // ---- block combine: parallel over 4 waves ----
    if (lane == 0) { s_m[w] = m; s_l[w] = l; }
    __syncthreads();
    float M = fmaxf(fmaxf(s_m[0], s_m[1]), fmaxf(s_m[2], s_m[3]));
    float f = __expf(m - M);                 // wave-uniform
#pragma unroll
    for (int it = 0; it < 5; ++it)
        *reinterpret_cast<float4*>(&s_all[w][it * 256 + d0]) =
            make_float4(acc[it].x * f, acc[it].y * f, acc[it].z * f, acc[it].w * f);
    __syncthreads();

    if (threadIdx.x == 0) {
        float lt = s_l[0] * __expf(s_m[0] - M) + s_l[1] * __expf(s_m[1] - M)
                 + s_l[2] * __expf(s_m[2] - M) + s_l[3] * __expf(s_m[3] - M);
        pm[blk] = M; pl[blk] = lt;
    }
#pragma unroll
    for (int j = 0; j < 5; ++j) {
        int d = j * 256 + threadIdx.x;
        pacc[(size_t)blk * cD + d] =
            s_all[0][d] + s_all[1][d] + s_all[2][d] + s_all[3][d];
    }
}

// ============================================================================
// Merged post-attention chain: partial-combine -> Wv -> Wo -> LN+ReLU.
// Grid 640 x 256, all blocks co-resident; manual barriers ph=3,4,5.
// ============================================================================
__global__ __launch_bounds__(256, 3) void k_post(const float* __restrict__ pm,
                                                 const float* __restrict__ pl,
                                                 const float* __restrict__ pacc,
                                                 float* __restrict__ ectx,
                                                 const float* __restrict__ Wv,
                                                 const float* __restrict__ bv,
                                                 float* __restrict__ ctx,
                                                 const float* __restrict__ Wo,
                                                 const float* __restrict__ bo,
                                                 float* __restrict__ h,
                                                 const float* __restrict__ gamma,
                                                 const float* __restrict__ beta,
                                                 float* __restrict__ out,
                                                 int* gsync) {
    __shared__ float red[8];
    int bid = blockIdx.x, tid = threadIdx.x;
    int* cnt = gsync;
    int* sense = gsync + 32;

    // ---- phase A: combine 32 softmax partials per batch -> ectx (160 blocks) ----
    if (bid < 160) {
        int b = bid / 5, j = bid % 5;
        int d = j * 256 + tid;
        float M = -INFINITY;
        for (int i = 0; i < 32; ++i) M = fmaxf(M, pm[b * 32 + i]);
        float L = 0.f, a = 0.f;
        for (int i = 0; i < 32; ++i) {
            float wf = __expf(pm[b * 32 + i] - M);
            L += pl[b * 32 + i] * wf;
            a += wf * pacc[(size_t)(b * 32 + i) * cD + d];
        }
        ectx[b * cD + d] = a / L;
    }
    gbar(cnt, sense, GB, 3);

    // ---- phase B: ctx = ectx @ Wv^T + bv (all 640 blocks) ----
    dotT_wave(ectx, (size_t)cD, Wv, bv, ctx, bid, tid);
    gbar(cnt, sense, GB, 4);

    // ---- phase C: h = ctx @ Wo^T + bo (all 640 blocks) ----
    dotT_wave(ctx, (size_t)cD, Wo, bo, h, bid, tid);
    gbar(cnt, sense, GB, 5);

    // ---- phase D: LayerNorm + ReLU (32 blocks) ----
    if (bid < cB) {
        int wid = tid >> 6, lane = tid & 63;
        float v[5];
        float sum = 0.f;
#pragma unroll
        for (int j = 0; j < 5; ++j) {
            v[j] = h[bid * cD + tid + 256 * j];
            sum += v[j];
        }
#pragma unroll
        for (int off = 32; off; off >>= 1) sum += __shfl_xor(sum, off, 64);
        if (lane == 0) red[wid] = sum;
        __syncthreads();
        float mu = (red[0] + red[1] + red[2] + red[3]) * (1.f / cD);
        float vs = 0.f;
#pragma unroll
        for (int j = 0; j < 5; ++j) { float t = v[j] - mu; vs += t * t; }
#pragma unroll
        for (int off = 32; off; off >>= 1) vs += __shfl_xor(vs, off, 64);
        if (lane == 0) red[4 + wid] = vs;
        __syncthreads();
        float var = (red[4] + red[5] + red[6] + red[7]) * (1.f / cD);
        float inv = rsqrtf(var + LN_EPS);
#pragma unroll
        for (int j = 0; j < 5; ++j) {
            int idx = tid + 256 * j;
            float o = (v[j] - mu) * inv * gamma[idx] + beta[idx];
            out[bid * cD + idx] = fmaxf(o, 0.f);
        }
    }
}

extern "C" void kernel_launch(void* const* d_in, const int* in_sizes, int n_in,
                              void* d_out, int out_size, void* d_ws, size_t ws_size,
                              hipStream_t stream) {
    const float* emb   = (const float*)d_in[0];
    const int*   mask  = (const int*)d_in[1];
    const float* Wq    = (const float*)d_in[2];
    const float* bq    = (const float*)d_in[3];
    const float* Wk    = (const float*)d_in[4];
    const float* bk    = (const float*)d_in[5];
    const float* Wv    = (const float*)d_in[6];
    const float* bv    = (const float*)d_in[7];
    const float* Wo    = (const float*)d_in[8];
    const float* bo    = (const float*)d_in[9];
    const float* gamma = (const float*)d_in[10];
    const float* beta  = (const float*)d_in[11];

    float* ws   = (float*)d_ws;
    float* part = ws;                        // 80*32*1280 = 3,276,800
    float* q0   = part + NKC * cB * cD;      // 40960
    float* qk   = q0 + cB * cD;              // 40960
    float* qb   = qk + cB * cD;              // 32
    float* pm   = qb + cB;                   // 1024
    float* pl   = pm + 1024;                 // 1024
    float* pacc = pl + 1024;                 // 1024*1280
    float* ectx = pacc + (size_t)1024 * cD;  // 40960
    float* ctx  = ectx + cB * cD;            // 40960
    float* h    = ctx + cB * cD;             // 40960
    int*   gsy  = (int*)(h + cB * cD);       // 64 ints: cnt @0, sense @32

    // zero the barrier state (graph-capture-safe; harness uses memsetAsync too)
    hipMemsetAsync(gsy, 0, 64 * sizeof(int), stream);

    // D1: q0 -> qk partials -> qk reduce + qb (merged, manual barriers)
    k_pre<<<GB, 256, 0, stream>>>(emb, Wq, bq, Wk, bk, q0, part, qk, qb, gsy);
    // D2: fused scores + softmax + weighted emb sum (the BW-floor kernel)
    k_attn<<<cB * 32, 256, 0, stream>>>(emb, qk, qb, mask, pm, pl, pacc);
    // D3: partial combine -> Wv -> Wo -> LN+ReLU (merged, manual barriers)
    k_post<<<GB, 256, 0, stream>>>(pm, pl, pacc, ectx, Wv, bv, ctx, Wo, bo, h,
                                   gamma, beta, (float*)d_out, gsy);
}

// Round 3
// 345.242 us; speedup vs baseline: 1.4052x; 1.4052x over previous
//
#include <hip/hip_runtime.h>

constexpr int cB = 32;
constexpr int cS = 1024;
constexpr int cD = 1280;
constexpr int KC = 16;          // k-chunk for split-K qk matmul
constexpr int NKC = cD / KC;    // 80 k-chunks
constexpr int NNC = cD / 256;   // 5 n-chunks

#define LN_EPS 1e-5f
#define MASK_FILL -1e9f
#define SCALE 0.02795084971874737f   // 1280^-0.5

// ============================================================================
// Row-dot matmul vs W^T:  out[b*cD+n] = bias[n] + dot(A[b,:], W[n,:])
// Grid 640 x 256 (2560 waves). Wave owns one W row (read once into regs),
// loops 16 batches with independent loads -> deep ILP, no atomics.
// ============================================================================
__global__ __launch_bounds__(256) void k_dotT(const float* __restrict__ A,
                                              size_t lda,
                                              const float* __restrict__ W,
                                              const float* __restrict__ bias,
                                              float* __restrict__ out) {
    int w = threadIdx.x >> 6, lane = threadIdx.x & 63;
    int gw = blockIdx.x * 4 + w;            // 0..2559
    int n = gw >> 1;                        // W row
    int bh = (gw & 1) * 16;                 // batch half
    int d0 = lane * 4;

    float4 wr[5];
#pragma unroll
    for (int it = 0; it < 5; ++it)
        wr[it] = *reinterpret_cast<const float4*>(W + (size_t)n * cD + it * 256 + d0);
    float bn = bias[n];

#pragma unroll
    for (int bi = 0; bi < 16; ++bi) {
        int b = bh + bi;
        const float* a = A + (size_t)b * lda + d0;
        float4 av[5];
#pragma unroll
        for (int it = 0; it < 5; ++it)
            av[it] = *reinterpret_cast<const float4*>(a + it * 256);
        float dot = 0.f;
#pragma unroll
        for (int it = 0; it < 5; ++it)
            dot += av[it].x * wr[it].x + av[it].y * wr[it].y
                 + av[it].z * wr[it].z + av[it].w * wr[it].w;
#pragma unroll
        for (int off = 32; off; off >>= 1) dot += __shfl_xor(dot, off, 64);
        if (lane == 0) out[b * cD + n] = dot + bn;
    }
}

// ============================================================================
// Split-K phase 1 (no atomics), B row-major [K,N]:
//   part[kc][b][n] = sum_{k in chunk} A[b,k] * B[k,n]
// Grid 400 = 5 nc x 80 kc. A loads wave-uniform -> s_load.
// ============================================================================
__global__ __launch_bounds__(256) void k_mm_p1(const float* __restrict__ A,
                                               const float* __restrict__ B,
                                               float* __restrict__ part) {
    int t = threadIdx.x;
    int nc = blockIdx.x % NNC, kc = blockIdx.x / NNC;
    int n0 = nc * 256, k0 = kc * KC;

    float w[KC];
#pragma unroll
    for (int kk = 0; kk < KC; ++kk)
        w[kk] = B[(size_t)(k0 + kk) * cD + n0 + t];   // coalesced

#pragma unroll
    for (int b = 0; b < cB; ++b) {
        const float* Ab = A + (size_t)b * cD + k0;    // wave-uniform -> s_load
        float a0 = 0.f, a1 = 0.f, a2 = 0.f, a3 = 0.f;
#pragma unroll
        for (int kk = 0; kk < KC; kk += 4) {
            a0 += Ab[kk + 0] * w[kk + 0];
            a1 += Ab[kk + 1] * w[kk + 1];
            a2 += Ab[kk + 2] * w[kk + 2];
            a3 += Ab[kk + 3] * w[kk + 3];
        }
        part[(size_t)kc * (cB * cD) + b * cD + n0 + t] = (a0 + a1) + (a2 + a3);
    }
}

// ---------------- phase 2: qk = sum partials ; last block: qb = q0.bk --------
__global__ __launch_bounds__(256) void k_mm_red_qb(const float* __restrict__ part,
                                                   const float* __restrict__ q0,
                                                   const float* __restrict__ bk,
                                                   float* __restrict__ qk,
                                                   float* __restrict__ qb) {
    if (blockIdx.x < 160) {
        int i = blockIdx.x * 256 + threadIdx.x;       // 0..cB*cD-1
        float s = 0.f;
#pragma unroll
        for (int c = 0; c < NKC; ++c) s += part[(size_t)c * (cB * cD) + i];
        qk[i] = s;
    } else {
        int w = threadIdx.x >> 6, lane = threadIdx.x & 63;
        int d0 = lane * 4;
        float4 bkr[5];
#pragma unroll
        for (int it = 0; it < 5; ++it)
            bkr[it] = *reinterpret_cast<const float4*>(bk + it * 256 + d0);
#pragma unroll
        for (int r = 0; r < 8; ++r) {
            int b = w * 8 + r;
            float dot = 0.f;
#pragma unroll
            for (int it = 0; it < 5; ++it) {
                float4 qv = *reinterpret_cast<const float4*>(q0 + b * cD + it * 256 + d0);
                dot += qv.x * bkr[it].x + qv.y * bkr[it].y
                     + qv.z * bkr[it].z + qv.w * bkr[it].w;
            }
#pragma unroll
            for (int off = 32; off; off >>= 1) dot += __shfl_xor(dot, off, 64);
            if (lane == 0) qb[b] = dot;
        }
    }
}

// ============================================================================
// Fused flash-style: scores + online softmax + weighted emb sum.
// Grid: b*32 + sc ; block 256 = 4 waves ; wave handles 8 consecutive s-rows.
// v3: software-pipelined 2-deep (erA/erB, statically unrolled): row r+1's
// 20 float4 loads are issued BEFORE row r's dot/reduce/exp/acc chain, so
// ~640 loads/CU stay in flight and the ~400-cy reduce tail is hidden.
// Per-row arithmetic order identical to the verified kernel (bit-identical).
// ============================================================================
__global__ __launch_bounds__(256) void k_attn(const float* __restrict__ emb,
                                              const float* __restrict__ qk,
                                              const float* __restrict__ qb,
                                              const int* __restrict__ mask,
                                              float* __restrict__ pm,
                                              float* __restrict__ pl,
                                              float* __restrict__ pacc) {
    __shared__ float s_all[4][cD];
    __shared__ float s_m[4], s_l[4];
    int blk = blockIdx.x;
    int b = blk >> 5, sc = blk & 31;
    int w = threadIdx.x >> 6, lane = threadIdx.x & 63;
    int d0 = lane * 4;

    float4 qkr[5];
#pragma unroll
    for (int it = 0; it < 5; ++it)
        qkr[it] = *reinterpret_cast<const float4*>(qk + b * cD + it * 256 + d0);
    float qbv = qb[b];

    float m = -INFINITY, l = 0.f;
    float4 acc[5];
#pragma unroll
    for (int it = 0; it < 5; ++it) acc[it] = make_float4(0.f, 0.f, 0.f, 0.f);

    int s0 = sc * 32 + w * 8;
    const float* ebase = emb + (size_t)(b * cS + s0) * cD + d0;

    // process one row given its preloaded registers (verbatim math from v0)
#define ATTN_ROW(rIdx, er)                                                     \
    {                                                                          \
        int s = s0 + (rIdx);                                                   \
        float dot = 0.f;                                                       \
        _Pragma("unroll")                                                      \
        for (int it = 0; it < 5; ++it)                                         \
            dot += er[it].x * qkr[it].x + er[it].y * qkr[it].y                 \
                 + er[it].z * qkr[it].z + er[it].w * qkr[it].w;                \
        _Pragma("unroll")                                                      \
        for (int off = 32; off; off >>= 1) dot += __shfl_xor(dot, off, 64);    \
        float scv = (mask[b * cS + s] == 0) ? MASK_FILL : (dot + qbv) * SCALE; \
        if (scv > m) {                                                         \
            float f = __expf(m - scv);                                         \
            l *= f;                                                            \
            _Pragma("unroll")                                                  \
            for (int it = 0; it < 5; ++it) {                                   \
                acc[it].x *= f; acc[it].y *= f;                                \
                acc[it].z *= f; acc[it].w *= f;                                \
            }                                                                  \
            m = scv;                                                           \
        }                                                                      \
        float p = __expf(scv - m);                                             \
        l += p;                                                                \
        _Pragma("unroll")                                                      \
        for (int it = 0; it < 5; ++it) {                                       \
            acc[it].x += p * er[it].x; acc[it].y += p * er[it].y;              \
            acc[it].z += p * er[it].z; acc[it].w += p * er[it].w;              \
        }                                                                      \
    }

    float4 erA[5], erB[5];
    // prologue: preload row 0
#pragma unroll
    for (int it = 0; it < 5; ++it)
        erA[it] = *reinterpret_cast<const float4*>(ebase + it * 256);

#pragma unroll
    for (int rr = 0; rr < 8; rr += 2) {
        // issue row rr+1 loads, then compute row rr (loads in flight over it)
#pragma unroll
        for (int it = 0; it < 5; ++it)
            erB[it] = *reinterpret_cast<const float4*>(
                ebase + (size_t)(rr + 1) * cD + it * 256);
        ATTN_ROW(rr, erA);
        // issue row rr+2 loads, then compute row rr+1
        if (rr + 2 < 8) {
#pragma unroll
            for (int it = 0; it < 5; ++it)
                erA[it] = *reinterpret_cast<const float4*>(
                    ebase + (size_t)(rr + 2) * cD + it * 256);
        }
        ATTN_ROW(rr + 1, erB);
    }
#undef ATTN_ROW

    // ---- block combine: parallel over 4 waves ----
    if (lane == 0) { s_m[w] = m; s_l[w] = l; }
    __syncthreads();
    float M = fmaxf(fmaxf(s_m[0], s_m[1]), fmaxf(s_m[2], s_m[3]));
    float f = __expf(m - M);                 // wave-uniform
#pragma unroll
    for (int it = 0; it < 5; ++it)
        *reinterpret_cast<float4*>(&s_all[w][it * 256 + d0]) =
            make_float4(acc[it].x * f, acc[it].y * f, acc[it].z * f, acc[it].w * f);
    __syncthreads();

    if (threadIdx.x == 0) {
        float lt = s_l[0] * __expf(s_m[0] - M) + s_l[1] * __expf(s_m[1] - M)
                 + s_l[2] * __expf(s_m[2] - M) + s_l[3] * __expf(s_m[3] - M);
        pm[blk] = M; pl[blk] = lt;
    }
#pragma unroll
    for (int j = 0; j < 5; ++j) {
        int d = j * 256 + threadIdx.x;
        pacc[(size_t)blk * cD + d] =
            s_all[0][d] + s_all[1][d] + s_all[2][d] + s_all[3][d];
    }
}

// ---------------- combine 32 partials per batch -> ectx ----------------------
__global__ __launch_bounds__(256) void k_attn_red(const float* __restrict__ pm,
                                                  const float* __restrict__ pl,
                                                  const float* __restrict__ pacc,
                                                  float* __restrict__ ectx) {
    int b = blockIdx.x / 5, j = blockIdx.x % 5;
    int d = j * 256 + threadIdx.x;
    float M = -INFINITY;
    for (int i = 0; i < 32; ++i) M = fmaxf(M, pm[b * 32 + i]);
    float L = 0.f, a = 0.f;
    for (int i = 0; i < 32; ++i) {
        float wf = __expf(pm[b * 32 + i] - M);
        L += pl[b * 32 + i] * wf;
        a += wf * pacc[(size_t)(b * 32 + i) * cD + d];
    }
    ectx[b * cD + d] = a / L;
}

// ---------------- LayerNorm + ReLU -------------------------------------------
__global__ __launch_bounds__(256) void k_ln(const float* __restrict__ h,
                                            const float* __restrict__ gamma,
                                            const float* __restrict__ beta,
                                            float* __restrict__ out) {
    int b = blockIdx.x;
    __shared__ float red[8];
    int wid = threadIdx.x >> 6, lane = threadIdx.x & 63;
    float v[5];
    float sum = 0.f;
#pragma unroll
    for (int j = 0; j < 5; ++j) {
        v[j] = h[b * cD + threadIdx.x + 256 * j];
        sum += v[j];
    }
#pragma unroll
    for (int off = 32; off; off >>= 1) sum += __shfl_xor(sum, off, 64);
    if (lane == 0) red[wid] = sum;
    __syncthreads();
    float mu = (red[0] + red[1] + red[2] + red[3]) * (1.f / cD);
    float vs = 0.f;
#pragma unroll
    for (int j = 0; j < 5; ++j) { float t = v[j] - mu; vs += t * t; }
#pragma unroll
    for (int off = 32; off; off >>= 1) vs += __shfl_xor(vs, off, 64);
    if (lane == 0) red[4 + wid] = vs;
    __syncthreads();
    float var = (red[4] + red[5] + red[6] + red[7]) * (1.f / cD);
    float inv = rsqrtf(var + LN_EPS);
#pragma unroll
    for (int j = 0; j < 5; ++j) {
        int idx = threadIdx.x + 256 * j;
        float o = (v[j] - mu) * inv * gamma[idx] + beta[idx];
        out[b * cD + idx] = fmaxf(o, 0.f);
    }
}

extern "C" void kernel_launch(void* const* d_in, const int* in_sizes, int n_in,
                              void* d_out, int out_size, void* d_ws, size_t ws_size,
                              hipStream_t stream) {
    const float* emb   = (const float*)d_in[0];
    const int*   mask  = (const int*)d_in[1];
    const float* Wq    = (const float*)d_in[2];
    const float* bq    = (const float*)d_in[3];
    const float* Wk    = (const float*)d_in[4];
    const float* bk    = (const float*)d_in[5];
    const float* Wv    = (const float*)d_in[6];
    const float* bv    = (const float*)d_in[7];
    const float* Wo    = (const float*)d_in[8];
    const float* bo    = (const float*)d_in[9];
    const float* gamma = (const float*)d_in[10];
    const float* beta  = (const float*)d_in[11];

    float* ws   = (float*)d_ws;
    float* part = ws;                        // 80*32*1280 = 3,276,800
    float* q0   = part + NKC * cB * cD;      // 40960
    float* qk   = q0 + cB * cD;              // 40960
    float* qb   = qk + cB * cD;              // 32
    float* pm   = qb + cB;                   // 1024
    float* pl   = pm + 1024;                 // 1024
    float* pacc = pl + 1024;                 // 1024*1280
    float* ectx = pacc + (size_t)1024 * cD;  // 40960
    float* ctx  = ectx + cB * cD;            // 40960
    float* h    = ctx + cB * cD;             // 40960

    // q0 = emb[:,0,:] @ Wq^T + bq       (row-dot, 2560 waves)
    k_dotT<<<640, 256, 0, stream>>>(emb, (size_t)cS * cD, Wq, bq, q0);
    // qk = q0 @ Wk  (split-K, 400 blocks, no atomics)
    k_mm_p1<<<NNC * NKC, 256, 0, stream>>>(q0, Wk, part);
    // qk reduce + qb = q0 . bk
    k_mm_red_qb<<<161, 256, 0, stream>>>(part, q0, bk, qk, qb);
    // fused scores + softmax + weighted emb sum (2-deep pipelined)
    k_attn<<<cB * 32, 256, 0, stream>>>(emb, qk, qb, mask, pm, pl, pacc);
    k_attn_red<<<160, 256, 0, stream>>>(pm, pl, pacc, ectx);
    // ctx = ectx @ Wv^T + bv            (row-dot)
    k_dotT<<<640, 256, 0, stream>>>(ectx, (size_t)cD, Wv, bv, ctx);
    // h = ctx @ Wo^T + bo               (row-dot)
    k_dotT<<<640, 256, 0, stream>>>(ctx, (size_t)cD, Wo, bo, h);
    // LayerNorm + ReLU
    k_ln<<<cB, 256, 0, stream>>>(h, gamma, beta, (float*)d_out);
}